// Round 12
// baseline (261.812 us; speedup 1.0000x reference)
//
#include <hip/hip_runtime.h>
#include <math.h>

typedef __attribute__((ext_vector_type(8))) short bf16x8;
typedef __attribute__((ext_vector_type(4))) float f32x4;
typedef __attribute__((ext_vector_type(16))) float f32x16;

#define HID 2048
#define SEQ 2048
#define NH  16
#define DH  128
// QK_SCALE * log2(e), folded into Q at the QKV epilogue so softmax is exp2-direct
#define QS_LOG2E 0.0318793607f

__device__ __forceinline__ ushort f2bf(float f) {
  union { float f; unsigned u; } v; v.f = f;
  unsigned r = v.u + 0x7fffu + ((v.u >> 16) & 1u);
  return (ushort)(r >> 16);
}

// async global->LDS, 16B per lane. lds ptr must be wave-uniform; HW adds lane*16.
__device__ __forceinline__ void gload16(const ushort* g, ushort* l) {
  __builtin_amdgcn_global_load_lds((const __attribute__((address_space(1))) void*)g,
                                   (__attribute__((address_space(3))) void*)l,
                                   16, 0, 0);
}

#define VMCNT(n) asm volatile("s_waitcnt vmcnt(" #n ")" ::: "memory")
#define LGKM0()  do { asm volatile("s_waitcnt lgkmcnt(0)" ::: "memory"); \
                      __builtin_amdgcn_sched_barrier(0); } while (0)
#define ABAR()   asm volatile("s_barrier" ::: "memory")

// ---------- fused transpose fp32 [2048][2048] -> bf16 [2048][2048] (Wt[n][k] = W[k][n]) ----------
__global__ __launch_bounds__(256) void k_transpose4(const float* __restrict__ W0,
                                                    const float* __restrict__ W1,
                                                    const float* __restrict__ W2,
                                                    const float* __restrict__ W3,
                                                    ushort* __restrict__ T0,
                                                    ushort* __restrict__ T3) {
  __shared__ float t[32][33];
  int z = blockIdx.z;
  const float* W = (z == 0) ? W0 : (z == 1) ? W1 : (z == 2) ? W2 : W3;
  ushort* Wt = (z == 3) ? T3 : (T0 + (size_t)z * 2048 * 2048);
  int n0 = blockIdx.x * 32, k0 = blockIdx.y * 32;
  int tx = threadIdx.x, ty = threadIdx.y;
  for (int i = ty; i < 32; i += 8)
    t[i][tx] = W[(size_t)(k0 + i) * HID + n0 + tx];
  __syncthreads();
  for (int i = ty; i < 32; i += 8)
    Wt[(size_t)(n0 + i) * HID + k0 + tx] = f2bf(t[tx][i]);
}

// ---------- RMSNorm: x fp32 [4096][2048] -> xn bf16 ----------
__global__ __launch_bounds__(256) void k_rmsnorm(const float* __restrict__ x,
                                                 const float* __restrict__ w,
                                                 ushort* __restrict__ xn) {
  int row = blockIdx.x;
  const float* xr = x + (size_t)row * HID;
  int base = threadIdx.x * 8;
  float4 a = *(const float4*)(xr + base);
  float4 c = *(const float4*)(xr + base + 4);
  float ss = a.x*a.x + a.y*a.y + a.z*a.z + a.w*a.w
           + c.x*c.x + c.y*c.y + c.z*c.z + c.w*c.w;
  #pragma unroll
  for (int off = 32; off > 0; off >>= 1) ss += __shfl_xor(ss, off);
  __shared__ float red[4];
  if ((threadIdx.x & 63) == 0) red[threadIdx.x >> 6] = ss;
  __syncthreads();
  float tot = red[0] + red[1] + red[2] + red[3];
  float sc = rsqrtf(tot * (1.0f / HID) + 1e-5f);
  float4 wa = *(const float4*)(w + base);
  float4 wc = *(const float4*)(w + base + 4);
  ushort h[8];
  h[0] = f2bf(a.x * sc * wa.x); h[1] = f2bf(a.y * sc * wa.y);
  h[2] = f2bf(a.z * sc * wa.z); h[3] = f2bf(a.w * sc * wa.w);
  h[4] = f2bf(c.x * sc * wc.x); h[5] = f2bf(c.y * sc * wc.y);
  h[6] = f2bf(c.z * sc * wc.z); h[7] = f2bf(c.w * sc * wc.w);
  int4 pk;
  pk.x = h[0] | ((int)h[1] << 16);
  pk.y = h[2] | ((int)h[3] << 16);
  pk.z = h[4] | ((int)h[5] << 16);
  pk.w = h[6] | ((int)h[7] << 16);
  *(int4*)&xn[(size_t)row * HID + base] = pk;
}

// ---------- GEMM v11: m201-style 8-phase micro-interleave on R11's regions ----------
// C = A[M][K] * Bt[N][K]^T, bf16.  BM=BN=256, BK=64 (2 kh-regions of k32),
// 8 waves (2Mx4N), per-wave 128x64.  LDS [2buf][2kh][A 16KB | B 16KB] = 128KB.
// R11 diagnosis: one fat phase (12 ds + 32 MFMA) makes all waves read LDS
// simultaneously then MFMA simultaneously -> resources ALTERNATE (~2570 cyc vs
// 1157 LDS + 1030 MFMA content).  m201's fix, ported here: 4 micro-phases per
// K-tile, each {ds 4-8 reads; stage 2 gloads; BAR; lgkm0; setprio1; 16 MFMA;
// setprio0; BAR} -> waves de-phase, MFMA clusters cover other waves' ds_reads.
// vmcnt placement (hand-retraced): trailing barriers of ph1/ph3 carry vmcnt(8),
// validating each kh-region BEFORE its first reader; outstanding peaks at 12,
// never drained in-loop.  Staging: ph0/ph1 stage kh1(t+1).A/.B, ph2/ph3 stage
// kh0(t+2).A/.B.  WAR: re-staged region's readers all passed the prior trailing
// barrier (reads consumed by MFMAs).  Swizzle: R11's cp = ck^((row>>1)&3) on
// 64B rows (measured 0 conflicts).
// Epilogue: bn<8 -> Q*QS_LOG2E; bn<16 -> K; bn>=16 -> V transposed (8B packed).
__global__ __launch_bounds__(512, 2) void k_gemm11(const ushort* __restrict__ A,
                                                   const ushort* __restrict__ Bt,
                                                   ushort* __restrict__ obf,
                                                   ushort* __restrict__ vt) {
  constexpr int K = 2048;
  __shared__ ushort lds[8][8192];   // [buf*4 + kh*2 + m]  m: 0=A, 1=B
  const int tid = threadIdx.x;
  const int lane = tid & 63, w = tid >> 6;
  const int wm = w >> 2, wn = w & 3;     // 2M x 4N waves
  const int g = lane >> 4, l15 = lane & 15;
  const int bm = blockIdx.y, bn = blockIdx.x;

  f32x4 acc[8][4];
  #pragma unroll
  for (int i = 0; i < 8; ++i)
    #pragma unroll
    for (int j = 0; j < 4; ++j) acc[i][j] = f32x4{0.f, 0.f, 0.f, 0.f};

  // staging sources (R11): slot = L*512 + tid -> row = slot>>2, cp = slot&3,
  // src chunk ck = cp ^ ((row>>1)&3)  (inverse of the read swizzle)
  const ushort* pA[2][2];
  const ushort* pB[2][2];
  #pragma unroll
  for (int kh = 0; kh < 2; ++kh)
    #pragma unroll
    for (int L = 0; L < 2; ++L) {
      int row = L * 128 + w * 16 + (lane >> 2);
      int ck = (lane & 3) ^ ((row >> 1) & 3);
      pA[kh][L] = &A[(size_t)(bm * 256 + row) * K + kh * 32 + ck * 8];
      pB[kh][L] = &Bt[(size_t)(bn * 256 + row) * K + kh * 32 + ck * 8];
    }

  bf16x8 aF[4], aH[4], bF[4];

  auto stageA = [&](int buf, int kh) {
    ushort* ra = lds[buf * 4 + kh * 2 + 0];
    #pragma unroll
    for (int L = 0; L < 2; ++L) {
      gload16(pA[kh][L], ra + (L * 8 + w) * 512);
      pA[kh][L] += 64;
    }
  };
  auto stageB = [&](int buf, int kh) {
    ushort* rb = lds[buf * 4 + kh * 2 + 1];
    #pragma unroll
    for (int L = 0; L < 2; ++L) {
      gload16(pB[kh][L], rb + (L * 8 + w) * 512);
      pB[kh][L] += 64;
    }
  };
  auto dsAlo = [&](int buf, int kh) {
    const ushort* ra = lds[buf * 4 + kh * 2 + 0];
    #pragma unroll
    for (int i = 0; i < 4; ++i) {
      int row = wm * 128 + i * 16 + l15;
      aF[i] = *(const bf16x8*)&ra[row * 32 + ((g ^ ((row >> 1) & 3)) * 8)];
    }
  };
  auto dsAhi = [&](int buf, int kh) {
    const ushort* ra = lds[buf * 4 + kh * 2 + 0];
    #pragma unroll
    for (int i = 0; i < 4; ++i) {
      int row = wm * 128 + (i + 4) * 16 + l15;
      aH[i] = *(const bf16x8*)&ra[row * 32 + ((g ^ ((row >> 1) & 3)) * 8)];
    }
  };
  auto dsB4 = [&](int buf, int kh) {
    const ushort* rb = lds[buf * 4 + kh * 2 + 1];
    #pragma unroll
    for (int j = 0; j < 4; ++j) {
      int row = wn * 64 + j * 16 + l15;
      bF[j] = *(const bf16x8*)&rb[row * 32 + ((g ^ ((row >> 1) & 3)) * 8)];
    }
  };
  auto MMlo = [&]() {   // 16 MFMA: i0-3 x j0-3
    __builtin_amdgcn_s_setprio(1);
    #pragma unroll
    for (int i = 0; i < 4; ++i)
      #pragma unroll
      for (int j = 0; j < 4; ++j)
        acc[i][j] = __builtin_amdgcn_mfma_f32_16x16x32_bf16(aF[i], bF[j], acc[i][j], 0, 0, 0);
    __builtin_amdgcn_s_setprio(0);
  };
  auto MMhi = [&]() {   // 16 MFMA: i4-7 x j0-3
    __builtin_amdgcn_s_setprio(1);
    #pragma unroll
    for (int i = 0; i < 4; ++i)
      #pragma unroll
      for (int j = 0; j < 4; ++j)
        acc[4 + i][j] = __builtin_amdgcn_mfma_f32_16x16x32_bf16(aH[i], bF[j], acc[4 + i][j], 0, 0, 0);
    __builtin_amdgcn_s_setprio(0);
  };

  // prologue: kh0(0), kh1(0), kh0(1) = 12 loads; vmcnt(8) retires kh0(0)
  stageA(0, 0); stageB(0, 0);
  stageA(0, 1); stageB(0, 1);
  stageA(1, 0); stageB(1, 0);
  VMCNT(8); ABAR();

  #pragma unroll 1
  for (int t = 0; t < 30; ++t) {
    const int b = t & 1, nb = b ^ 1;
    // ph0: kh0 lo
    dsAlo(b, 0); dsB4(b, 0); stageA(nb, 1);
    ABAR(); LGKM0(); MMlo(); ABAR();
    // ph1: kh0 hi ; trailing vmcnt validates kh1(t) for ph2
    dsAhi(b, 0); stageB(nb, 1);
    ABAR(); LGKM0(); MMhi(); VMCNT(8); ABAR();
    // ph2: kh1 lo
    dsAlo(b, 1); dsB4(b, 1); stageA(b, 0);
    ABAR(); LGKM0(); MMlo(); ABAR();
    // ph3: kh1 hi ; trailing vmcnt validates kh0(t+1) for next ph0
    dsAhi(b, 1); stageB(b, 0);
    ABAR(); LGKM0(); MMhi(); VMCNT(8); ABAR();
  }
  // t=30 (buf 0): stage only kh1(31)
  dsAlo(0, 0); dsB4(0, 0); stageA(1, 1);
  ABAR(); LGKM0(); MMlo(); ABAR();
  dsAhi(0, 0); stageB(1, 1);
  ABAR(); LGKM0(); MMhi(); VMCNT(8); ABAR();   // retires kh1(30)
  dsAlo(0, 1); dsB4(0, 1);
  ABAR(); LGKM0(); MMlo(); ABAR();
  dsAhi(0, 1);
  ABAR(); LGKM0(); MMhi(); VMCNT(4); ABAR();   // retires kh0(31)
  // t=31 (buf 1): drain
  dsAlo(1, 0); dsB4(1, 0);
  ABAR(); LGKM0(); MMlo(); ABAR();
  dsAhi(1, 0);
  ABAR(); LGKM0(); MMhi(); VMCNT(0); ABAR();   // retires kh1(31)
  dsAlo(1, 1); dsB4(1, 1);
  ABAR(); LGKM0(); MMlo(); ABAR();
  dsAhi(1, 1);
  LGKM0(); MMhi();

  // C/D layout: col = lane&15, row = (lane>>4)*4 + r
  int rbase = bm * 256 + wm * 128 + g * 4;
  int cbase = bn * 256 + wn * 64 + l15;
  if (bn < 16) {
    const float sc = (bn < 8) ? QS_LOG2E : 1.0f;
    #pragma unroll
    for (int i = 0; i < 8; ++i) {
      #pragma unroll
      for (int j = 0; j < 4; ++j) {
        int col = cbase + j * 16;
        #pragma unroll
        for (int r = 0; r < 4; ++r) {
          int row = rbase + i * 16 + r;
          obf[(size_t)row * 4096 + col] = f2bf(acc[i][j][r] * sc);
        }
      }
    }
  } else {
    // V: transposed store vt[(b,h,d)][s]; r-direction = s contiguous -> 8B packed
    #pragma unroll
    for (int i = 0; i < 8; ++i) {
      int rowb = rbase + i * 16;          // multiple of 4
      int b = rowb >> 11, s = rowb & 2047;
      #pragma unroll
      for (int j = 0; j < 4; ++j) {
        int nv = cbase + j * 16 - 4096;
        int h = nv >> 7, d = nv & 127;
        uint lo = (uint)f2bf(acc[i][j][0]) | ((uint)f2bf(acc[i][j][1]) << 16);
        uint hi = (uint)f2bf(acc[i][j][2]) | ((uint)f2bf(acc[i][j][3]) << 16);
        uint2 pk = {lo, hi};
        *(uint2*)&vt[(size_t)((b * NH + h) * DH + d) * SEQ + s] = pk;
      }
    }
  }
}

// ---------- GEMM (R2-structure): out-proj ----------
__global__ __launch_bounds__(256) void k_gemm7o(const ushort* __restrict__ A,
                                                const ushort* __restrict__ Bt,
                                                float* __restrict__ ofl,
                                                const float* __restrict__ resid,
                                                int K) {
  __shared__ ushort sA[128 * 64];
  __shared__ ushort sB[128 * 64];
  const int tid = threadIdx.x;
  const int lane = tid & 63, w = tid >> 6;
  const int wr = w >> 1, wc = w & 1;
  const int bm = blockIdx.y, bn = blockIdx.x;
  const int g = lane >> 4, l15 = lane & 15;
  f32x4 acc[4][4];
  #pragma unroll
  for (int i = 0; i < 4; ++i)
    #pragma unroll
    for (int j = 0; j < 4; ++j) acc[i][j] = f32x4{0.f, 0.f, 0.f, 0.f};

  const ushort* ap[4];
  const ushort* bp[4];
  ushort* la[4];
  ushort* lb[4];
  #pragma unroll
  for (int c = 0; c < 4; ++c) {
    int id = (w * 4 + c) * 64 + lane;
    int r = id >> 3, ck = id & 7;
    int ke = (ck ^ (r & 7)) * 8;
    ap[c] = &A[(size_t)(bm * 128 + r) * K + ke];
    bp[c] = &Bt[(size_t)(bn * 128 + r) * K + ke];
    la[c] = ((ushort*)sA) + (w * 4 + c) * 512;
    lb[c] = ((ushort*)sB) + (w * 4 + c) * 512;
  }

  const int nt = K / 64;
  #pragma unroll 1
  for (int t = 0; t < nt; ++t) {
    #pragma unroll
    for (int c = 0; c < 4; ++c) {
      gload16(ap[c], la[c]);
      gload16(bp[c], lb[c]);
      ap[c] += 64;
      bp[c] += 64;
    }
    __syncthreads();
    #pragma unroll
    for (int kk = 0; kk < 2; ++kk) {
      bf16x8 aF[4], bF[4];
      #pragma unroll
      for (int i = 0; i < 4; ++i) {
        int row = wr * 64 + i * 16 + l15;
        int cp = (kk * 4 + g) ^ (lane & 7);
        aF[i] = *(const bf16x8*)&sA[row * 64 + cp * 8];
      }
      #pragma unroll
      for (int j = 0; j < 4; ++j) {
        int row = wc * 64 + j * 16 + l15;
        int cp = (kk * 4 + g) ^ (lane & 7);
        bF[j] = *(const bf16x8*)&sB[row * 64 + cp * 8];
      }
      #pragma unroll
      for (int i = 0; i < 4; ++i)
        #pragma unroll
        for (int j = 0; j < 4; ++j)
          acc[i][j] = __builtin_amdgcn_mfma_f32_16x16x32_bf16(aF[i], bF[j], acc[i][j], 0, 0, 0);
    }
    __syncthreads();
  }

  int rbase = bm * 128 + wr * 64 + g * 4;
  int cbase = bn * 128 + wc * 64 + l15;
  #pragma unroll
  for (int i = 0; i < 4; ++i) {
    #pragma unroll
    for (int j = 0; j < 4; ++j) {
      int col = cbase + j * 16;
      #pragma unroll
      for (int r = 0; r < 4; ++r) {
        int row = rbase + i * 16 + r;
        ofl[(size_t)row * HID + col] = acc[i][j][r] + resid[(size_t)row * HID + col];
      }
    }
  }
}

// ---------- flash attention v5 (R10): balanced pairing + no-max exp2 softmax ----------
__global__ __launch_bounds__(256, 2) void k_attn5(const ushort* __restrict__ qk,
                                                  const ushort* __restrict__ vt,
                                                  ushort* __restrict__ aout) {
  __shared__ ushort sK[64 * 128];
  __shared__ ushort sV[128 * 64];
  const int tid = threadIdx.x;
  const int lane = tid & 63, w = tid >> 6;
  const int h2 = lane >> 5;
  const int l31 = lane & 31;
  const int bid = blockIdx.x;
  const int t = bid >> 3;
  const int u = t & 31, v = t >> 5;
  const int bh = (bid & 7) + 8 * (u & 3);
  const int qblk = v ? 15 - (u >> 2) : (u >> 2);
  const int b = bh >> 4, hh = bh & 15;
  const int q0w = qblk * 128 + w * 32;

  bf16x8 qf[8];
  {
    const ushort* qbase = qk + (size_t)(b * SEQ + q0w + l31) * 4096 + hh * DH;
    #pragma unroll
    for (int kk = 0; kk < 8; ++kk) qf[kk] = *(const bf16x8*)&qbase[kk * 16 + h2 * 8];
  }

  const ushort* kp[4];
  const ushort* vp[4];
  ushort* lk[4];
  ushort* lv[4];
  #pragma unroll
  for (int c = 0; c < 4; ++c) {
    int id = (w * 4 + c) * 64 + lane;
    int kr = id >> 4, ck = id & 15;
    kp[c] = qk + (size_t)(b * SEQ + kr) * 4096 + 2048 + hh * DH + ((ck ^ (kr & 7)) * 8);
    int dr = id >> 3, cv = id & 7;
    vp[c] = vt + (size_t)(bh * DH + dr) * SEQ + ((cv ^ (dr & 7)) * 8);
    lk[c] = ((ushort*)sK) + (size_t)(w * 4 + c) * 512;
    lv[c] = ((ushort*)sV) + (size_t)(w * 4 + c) * 512;
  }

  f32x16 accO[4];
  #pragma unroll
  for (int i = 0; i < 4; ++i)
    #pragma unroll
    for (int r = 0; r < 16; ++r) accO[i][r] = 0.f;
  float l_r = 0.f;

  const int ntile = 2 * qblk + 2;
  #pragma unroll 1
  for (int tt = 0; tt < ntile; ++tt) {
    const int t0 = tt * 64;
    #pragma unroll
    for (int c = 0; c < 4; ++c) {
      gload16(kp[c], lk[c]);
      gload16(vp[c], lv[c]);
      kp[c] += 64 * 4096;
      vp[c] += 64;
    }
    __syncthreads();

    if (t0 <= q0w + 31) {
      f32x16 accS[2];
      #pragma unroll
      for (int i = 0; i < 2; ++i)
        #pragma unroll
        for (int r = 0; r < 16; ++r) accS[i][r] = 0.f;
      #pragma unroll
      for (int kt = 0; kt < 2; ++kt) {
        const int row = kt * 32 + l31;
        #pragma unroll
        for (int kk = 0; kk < 8; ++kk) {
          const int cp = (kk * 2 + h2) ^ (lane & 7);
          bf16x8 kf = *(const bf16x8*)&sK[row * 128 + cp * 8];
          accS[kt] = __builtin_amdgcn_mfma_f32_32x32x16_bf16(kf, qf[kk], accS[kt], 0, 0, 0);
        }
      }
      float rs = 0.f;
      if (t0 + 63 <= q0w) {
        #pragma unroll
        for (int kt = 0; kt < 2; ++kt)
          #pragma unroll
          for (int r = 0; r < 16; ++r) {
            float p = __builtin_amdgcn_exp2f(accS[kt][r]);
            rs += p;
            accS[kt][r] = p;
          }
      } else {
        const int qa = q0w + l31;
        #pragma unroll
        for (int kt = 0; kt < 2; ++kt)
          #pragma unroll
          for (int r = 0; r < 16; ++r) {
            int ka = t0 + kt * 32 + (r & 3) + 8 * (r >> 2) + 4 * h2;
            float p = (ka <= qa) ? __builtin_amdgcn_exp2f(accS[kt][r]) : 0.f;
            rs += p;
            accS[kt][r] = p;
          }
      }
      rs += __shfl_xor(rs, 32);
      l_r += rs;

      uint W[2][4][2];
      #pragma unroll
      for (int kt = 0; kt < 2; ++kt)
        #pragma unroll
        for (int bq = 0; bq < 4; ++bq)
          #pragma unroll
          for (int w2 = 0; w2 < 2; ++w2) {
            uint u0 = __float_as_uint(accS[kt][bq * 4 + w2 * 2]);
            uint u1 = __float_as_uint(accS[kt][bq * 4 + w2 * 2 + 1]);
            W[kt][bq][w2] = (u0 >> 16) | (u1 & 0xffff0000u);
          }
      #pragma unroll
      for (int kc = 0; kc < 4; ++kc) {
        const int kt = kc >> 1, pq = kc & 1;
        uint X0 = W[kt][2 * pq][0],     X1 = W[kt][2 * pq][1];
        uint Y0 = W[kt][2 * pq + 1][0], Y1 = W[kt][2 * pq + 1][1];
        uint sx0 = (uint)__shfl_xor((int)X0, 32);
        uint sx1 = (uint)__shfl_xor((int)X1, 32);
        uint sy0 = (uint)__shfl_xor((int)Y0, 32);
        uint sy1 = (uint)__shfl_xor((int)Y1, 32);
        union { uint u[4]; bf16x8 v; } pu;
        pu.u[0] = h2 ? sy0 : X0;
        pu.u[1] = h2 ? sy1 : X1;
        pu.u[2] = h2 ? Y0 : sx0;
        pu.u[3] = h2 ? Y1 : sx1;
        #pragma unroll
        for (int ds = 0; ds < 4; ++ds) {
          const int dr = ds * 32 + l31;
          const int cp = (kc * 2 + h2) ^ (lane & 7);
          bf16x8 vf = *(const bf16x8*)&sV[dr * 64 + cp * 8];
          accO[ds] = __builtin_amdgcn_mfma_f32_32x32x16_bf16(pu.v, vf, accO[ds], 0, 0, 0);
        }
      }
    }
    __syncthreads();
  }

  float linv = 1.f / l_r;
  #pragma unroll
  for (int r = 0; r < 16; ++r) {
    int qrel = (r & 3) + 8 * (r >> 2) + 4 * h2;
    float li = __shfl(linv, qrel);
    #pragma unroll
    for (int ds = 0; ds < 4; ++ds) {
      aout[(size_t)(b * SEQ + q0w + qrel) * HID + hh * DH + ds * 32 + l31] =
          f2bf(accO[ds][r] * li);
    }
  }
}

extern "C" void kernel_launch(void* const* d_in, const int* in_sizes, int n_in,
                              void* d_out, int out_size, void* d_ws, size_t ws_size,
                              hipStream_t stream) {
  const float* x     = (const float*)d_in[0];
  const float* rms_w = (const float*)d_in[1];
  const float* Wq    = (const float*)d_in[2];
  const float* Wk    = (const float*)d_in[3];
  const float* Wv    = (const float*)d_in[4];
  const float* Wo    = (const float*)d_in[5];
  float* out = (float*)d_out;

  char* ws = (char*)d_ws;
  ushort* WqkvT = (ushort*)ws; ws += (size_t)6144 * 2048 * 2;  // [6144][2048]
  ushort* WoT   = (ushort*)ws; ws += (size_t)2048 * 2048 * 2;  // [2048][2048]
  ushort* xn    = (ushort*)ws; ws += (size_t)4096 * 2048 * 2;  // [4096][2048]
  ushort* qkbuf = (ushort*)ws; ws += (size_t)4096 * 4096 * 2;  // [4096][4096]
  ushort* vt    = (ushort*)ws; ws += (size_t)4096 * 2048 * 2;  // [(b,h,d)][2048]
  ushort* aout  = (ushort*)ws; ws += (size_t)4096 * 2048 * 2;  // [4096][2048]

  // fused weight transposes (4 matrices in one launch)
  k_transpose4<<<dim3(64, 64, 4), dim3(32, 8), 0, stream>>>(Wq, Wk, Wv, Wo, WqkvT, WoT);

  k_rmsnorm<<<4096, 256, 0, stream>>>(x, rms_w, xn);

  // QKV: M=4096, N=6144, K=2048.  256x256 tiles -> grid 24 x 16 (bn-fast).
  k_gemm11<<<dim3(24, 16), 512, 0, stream>>>(xn, WqkvT, qkbuf, vt);

  // attention: 512 blocks, balanced qblk pairing, all co-resident at 2/CU
  k_attn5<<<512, 256, 0, stream>>>(qkbuf, vt, aout);

  // out = attn @ Wo + x : M=4096, N=2048, K=2048
  k_gemm7o<<<dim3(16, 32), 256, 0, stream>>>(aout, WoT, out, x, 2048);
}

// Round 13
// 255.560 us; speedup vs baseline: 1.0245x; 1.0245x over previous
//
#include <hip/hip_runtime.h>
#include <math.h>

typedef __attribute__((ext_vector_type(8))) short bf16x8;
typedef __attribute__((ext_vector_type(4))) float f32x4;
typedef __attribute__((ext_vector_type(16))) float f32x16;

#define HID 2048
#define SEQ 2048
#define NH  16
#define DH  128
// QK_SCALE * log2(e), folded into Q at the QKV epilogue so softmax is exp2-direct
#define QS_LOG2E 0.0318793607f

__device__ __forceinline__ ushort f2bf(float f) {
  union { float f; unsigned u; } v; v.f = f;
  unsigned r = v.u + 0x7fffu + ((v.u >> 16) & 1u);
  return (ushort)(r >> 16);
}

// async global->LDS, 16B per lane. lds ptr must be wave-uniform; HW adds lane*16.
__device__ __forceinline__ void gload16(const ushort* g, ushort* l) {
  __builtin_amdgcn_global_load_lds((const __attribute__((address_space(1))) void*)g,
                                   (__attribute__((address_space(3))) void*)l,
                                   16, 0, 0);
}

#define VMCNT(n) asm volatile("s_waitcnt vmcnt(" #n ")" ::: "memory")
#define ABAR()   asm volatile("s_barrier" ::: "memory")

// ---------- fused prep: z<4 -> weight transpose fp32->bf16; z==4 -> RMSNorm ----------
// transpose: Wt[n][k] = bf16(W[k][n]) per 32x32 tile.  rmsnorm: row = by*64+bx.
// One launch: transpose blocks and rmsnorm blocks co-schedule across CUs.
__global__ __launch_bounds__(256) void k_prep(const float* __restrict__ W0,
                                              const float* __restrict__ W1,
                                              const float* __restrict__ W2,
                                              const float* __restrict__ W3,
                                              ushort* __restrict__ T0,
                                              ushort* __restrict__ T3,
                                              const float* __restrict__ x,
                                              const float* __restrict__ rw,
                                              ushort* __restrict__ xn) {
  const int z = blockIdx.z;
  if (z < 4) {
    __shared__ float t[32][33];
    const float* W = (z == 0) ? W0 : (z == 1) ? W1 : (z == 2) ? W2 : W3;
    ushort* Wt = (z == 3) ? T3 : (T0 + (size_t)z * 2048 * 2048);
    int n0 = blockIdx.x * 32, k0 = blockIdx.y * 32;
    int tx = threadIdx.x, ty = threadIdx.y;
    for (int i = ty; i < 32; i += 8)
      t[i][tx] = W[(size_t)(k0 + i) * HID + n0 + tx];
    __syncthreads();
    for (int i = ty; i < 32; i += 8)
      Wt[(size_t)(n0 + i) * HID + k0 + tx] = f2bf(t[tx][i]);
  } else {
    const int tid = threadIdx.y * 32 + threadIdx.x;
    const int row = blockIdx.y * 64 + blockIdx.x;
    const float* xr = x + (size_t)row * HID;
    int base = tid * 8;
    float4 a = *(const float4*)(xr + base);
    float4 c = *(const float4*)(xr + base + 4);
    float ss = a.x*a.x + a.y*a.y + a.z*a.z + a.w*a.w
             + c.x*c.x + c.y*c.y + c.z*c.z + c.w*c.w;
    #pragma unroll
    for (int off = 32; off > 0; off >>= 1) ss += __shfl_xor(ss, off);
    __shared__ float red[4];
    if ((tid & 63) == 0) red[tid >> 6] = ss;
    __syncthreads();
    float tot = red[0] + red[1] + red[2] + red[3];
    float sc = rsqrtf(tot * (1.0f / HID) + 1e-5f);
    float4 wa = *(const float4*)(rw + base);
    float4 wc = *(const float4*)(rw + base + 4);
    ushort h[8];
    h[0] = f2bf(a.x * sc * wa.x); h[1] = f2bf(a.y * sc * wa.y);
    h[2] = f2bf(a.z * sc * wa.z); h[3] = f2bf(a.w * sc * wa.w);
    h[4] = f2bf(c.x * sc * wc.x); h[5] = f2bf(c.y * sc * wc.y);
    h[6] = f2bf(c.z * sc * wc.z); h[7] = f2bf(c.w * sc * wc.w);
    int4 pk;
    pk.x = h[0] | ((int)h[1] << 16);
    pk.y = h[2] | ((int)h[3] << 16);
    pk.z = h[4] | ((int)h[5] << 16);
    pk.w = h[6] | ((int)h[7] << 16);
    *(int4*)&xn[(size_t)row * HID + base] = pk;
  }
}

// ---------- GEMM v10 (R11, measured best QKV): k-slice-region counted-vmcnt ----------
// BM=BN=256, BK=64, 8 waves (2Mx4N), per-wave 128x64.  LDS [2buf][2kh][A|B] 128KB.
// Cooperative staging; cadence 2 phases/tile, vmcnt(8) each, never drained in-loop.
// Swizzle cp = ck^((row>>1)&3) (measured 0 conflicts).
// Epilogue: bn<8 -> Q*QS_LOG2E; bn<16 -> K; bn>=16 -> V transposed (8B packed).
__global__ __launch_bounds__(512, 2) void k_gemm10(const ushort* __restrict__ A,
                                                   const ushort* __restrict__ Bt,
                                                   ushort* __restrict__ obf,
                                                   ushort* __restrict__ vt) {
  constexpr int K = 2048;
  __shared__ ushort lds[8][8192];   // [buf*4 + kh*2 + m]
  const int tid = threadIdx.x;
  const int lane = tid & 63, w = tid >> 6;
  const int wm = w >> 2, wn = w & 3;     // 2M x 4N waves
  const int g = lane >> 4, l15 = lane & 15;
  const int bm = blockIdx.y, bn = blockIdx.x;

  f32x4 acc[8][4];
  #pragma unroll
  for (int i = 0; i < 8; ++i)
    #pragma unroll
    for (int j = 0; j < 4; ++j) acc[i][j] = f32x4{0.f, 0.f, 0.f, 0.f};

  const ushort* pA[2][2];
  const ushort* pB[2][2];
  #pragma unroll
  for (int kh = 0; kh < 2; ++kh)
    #pragma unroll
    for (int L = 0; L < 2; ++L) {
      int row = L * 128 + w * 16 + (lane >> 2);
      int ck = (lane & 3) ^ ((row >> 1) & 3);
      pA[kh][L] = &A[(size_t)(bm * 256 + row) * K + kh * 32 + ck * 8];
      pB[kh][L] = &Bt[(size_t)(bn * 256 + row) * K + kh * 32 + ck * 8];
    }

  auto STAGE = [&](int buf, int kh) {
    ushort* ra = lds[buf * 4 + kh * 2 + 0];
    ushort* rb = lds[buf * 4 + kh * 2 + 1];
    #pragma unroll
    for (int L = 0; L < 2; ++L) {
      gload16(pA[kh][L], ra + (L * 8 + w) * 512);
      pA[kh][L] += 64;
    }
    #pragma unroll
    for (int L = 0; L < 2; ++L) {
      gload16(pB[kh][L], rb + (L * 8 + w) * 512);
      pB[kh][L] += 64;
    }
  };

  auto COMP = [&](int buf, int kh) {
    const ushort* ra = lds[buf * 4 + kh * 2 + 0];
    const ushort* rb = lds[buf * 4 + kh * 2 + 1];
    bf16x8 aF[8], bF[4];
    #pragma unroll
    for (int i = 0; i < 8; ++i) {
      int row = wm * 128 + i * 16 + l15;
      aF[i] = *(const bf16x8*)&ra[row * 32 + ((g ^ ((row >> 1) & 3)) * 8)];
    }
    #pragma unroll
    for (int j = 0; j < 4; ++j) {
      int row = wn * 64 + j * 16 + l15;
      bF[j] = *(const bf16x8*)&rb[row * 32 + ((g ^ ((row >> 1) & 3)) * 8)];
    }
    __builtin_amdgcn_s_setprio(1);
    #pragma unroll
    for (int i = 0; i < 8; ++i)
      #pragma unroll
      for (int j = 0; j < 4; ++j)
        acc[i][j] = __builtin_amdgcn_mfma_f32_16x16x32_bf16(aF[i], bF[j], acc[i][j], 0, 0, 0);
    __builtin_amdgcn_s_setprio(0);
  };

  STAGE(0, 0); STAGE(0, 1); STAGE(1, 0);

  #pragma unroll 1
  for (int t = 0; t < 30; ++t) {
    const int b = t & 1, nb = b ^ 1;
    VMCNT(8); ABAR();
    STAGE(nb, 1);
    COMP(b, 0);
    VMCNT(8); ABAR();
    STAGE(b, 0);
    COMP(b, 1);
  }
  VMCNT(8); ABAR(); STAGE(1, 1); COMP(0, 0);
  VMCNT(8); ABAR();               COMP(0, 1);
  VMCNT(4); ABAR(); COMP(1, 0);
  VMCNT(0); ABAR(); COMP(1, 1);

  int rbase = bm * 256 + wm * 128 + g * 4;
  int cbase = bn * 256 + wn * 64 + l15;
  if (bn < 16) {
    const float sc = (bn < 8) ? QS_LOG2E : 1.0f;
    #pragma unroll
    for (int i = 0; i < 8; ++i) {
      #pragma unroll
      for (int j = 0; j < 4; ++j) {
        int col = cbase + j * 16;
        #pragma unroll
        for (int r = 0; r < 4; ++r) {
          int row = rbase + i * 16 + r;
          obf[(size_t)row * 4096 + col] = f2bf(acc[i][j][r] * sc);
        }
      }
    }
  } else {
    #pragma unroll
    for (int i = 0; i < 8; ++i) {
      int rowb = rbase + i * 16;
      int b = rowb >> 11, s = rowb & 2047;
      #pragma unroll
      for (int j = 0; j < 4; ++j) {
        int nv = cbase + j * 16 - 4096;
        int h = nv >> 7, d = nv & 127;
        uint lo = (uint)f2bf(acc[i][j][0]) | ((uint)f2bf(acc[i][j][1]) << 16);
        uint hi = (uint)f2bf(acc[i][j][2]) | ((uint)f2bf(acc[i][j][3]) << 16);
        uint2 pk = {lo, hi};
        *(uint2*)&vt[(size_t)((b * NH + h) * DH + d) * SEQ + s] = pk;
      }
    }
  }
}

// ---------- GEMM (R2-structure): out-proj ----------
__global__ __launch_bounds__(256) void k_gemm7o(const ushort* __restrict__ A,
                                                const ushort* __restrict__ Bt,
                                                float* __restrict__ ofl,
                                                const float* __restrict__ resid,
                                                int K) {
  __shared__ ushort sA[128 * 64];
  __shared__ ushort sB[128 * 64];
  const int tid = threadIdx.x;
  const int lane = tid & 63, w = tid >> 6;
  const int wr = w >> 1, wc = w & 1;
  const int bm = blockIdx.y, bn = blockIdx.x;
  const int g = lane >> 4, l15 = lane & 15;
  f32x4 acc[4][4];
  #pragma unroll
  for (int i = 0; i < 4; ++i)
    #pragma unroll
    for (int j = 0; j < 4; ++j) acc[i][j] = f32x4{0.f, 0.f, 0.f, 0.f};

  const ushort* ap[4];
  const ushort* bp[4];
  ushort* la[4];
  ushort* lb[4];
  #pragma unroll
  for (int c = 0; c < 4; ++c) {
    int id = (w * 4 + c) * 64 + lane;
    int r = id >> 3, ck = id & 7;
    int ke = (ck ^ (r & 7)) * 8;
    ap[c] = &A[(size_t)(bm * 128 + r) * K + ke];
    bp[c] = &Bt[(size_t)(bn * 128 + r) * K + ke];
    la[c] = ((ushort*)sA) + (w * 4 + c) * 512;
    lb[c] = ((ushort*)sB) + (w * 4 + c) * 512;
  }

  const int nt = K / 64;
  #pragma unroll 1
  for (int t = 0; t < nt; ++t) {
    #pragma unroll
    for (int c = 0; c < 4; ++c) {
      gload16(ap[c], la[c]);
      gload16(bp[c], lb[c]);
      ap[c] += 64;
      bp[c] += 64;
    }
    __syncthreads();
    #pragma unroll
    for (int kk = 0; kk < 2; ++kk) {
      bf16x8 aF[4], bF[4];
      #pragma unroll
      for (int i = 0; i < 4; ++i) {
        int row = wr * 64 + i * 16 + l15;
        int cp = (kk * 4 + g) ^ (lane & 7);
        aF[i] = *(const bf16x8*)&sA[row * 64 + cp * 8];
      }
      #pragma unroll
      for (int j = 0; j < 4; ++j) {
        int row = wc * 64 + j * 16 + l15;
        int cp = (kk * 4 + g) ^ (lane & 7);
        bF[j] = *(const bf16x8*)&sB[row * 64 + cp * 8];
      }
      #pragma unroll
      for (int i = 0; i < 4; ++i)
        #pragma unroll
        for (int j = 0; j < 4; ++j)
          acc[i][j] = __builtin_amdgcn_mfma_f32_16x16x32_bf16(aF[i], bF[j], acc[i][j], 0, 0, 0);
    }
    __syncthreads();
  }

  int rbase = bm * 128 + wr * 64 + g * 4;
  int cbase = bn * 128 + wc * 64 + l15;
  #pragma unroll
  for (int i = 0; i < 4; ++i) {
    #pragma unroll
    for (int j = 0; j < 4; ++j) {
      int col = cbase + j * 16;
      #pragma unroll
      for (int r = 0; r < 4; ++r) {
        int row = rbase + i * 16 + r;
        ofl[(size_t)row * HID + col] = acc[i][j][r] + resid[(size_t)row * HID + col];
      }
    }
  }
}

// ---------- flash attention v6: R10 softmax/map + 2-deep counted-vmcnt dbuf ----------
// 4 waves x QBLK=32, KVBLK=64, 32x32x16, swapped QK^T, exp2-direct softmax.
// STAGE(t+1) issued BEFORE compute(t); vmcnt(8) leaves next tile's loads in
// flight under QK/PV MFMAs.  sK[2]+sV[2] = 64KB -> still 2 blocks/CU.
__global__ __launch_bounds__(256, 2) void k_attn6(const ushort* __restrict__ qk,
                                                  const ushort* __restrict__ vt,
                                                  ushort* __restrict__ aout) {
  __shared__ ushort sK[2][64 * 128];
  __shared__ ushort sV[2][128 * 64];
  const int tid = threadIdx.x;
  const int lane = tid & 63, w = tid >> 6;
  const int h2 = lane >> 5;
  const int l31 = lane & 31;
  const int bid = blockIdx.x;
  const int t = bid >> 3;
  const int u = t & 31, v = t >> 5;
  const int bh = (bid & 7) + 8 * (u & 3);
  const int qblk = v ? 15 - (u >> 2) : (u >> 2);
  const int b = bh >> 4, hh = bh & 15;
  const int q0w = qblk * 128 + w * 32;

  bf16x8 qf[8];
  {
    const ushort* qbase = qk + (size_t)(b * SEQ + q0w + l31) * 4096 + hh * DH;
    #pragma unroll
    for (int kk = 0; kk < 8; ++kk) qf[kk] = *(const bf16x8*)&qbase[kk * 16 + h2 * 8];
  }

  const ushort* kp[4];
  const ushort* vp[4];
  int lofs[4];
  #pragma unroll
  for (int c = 0; c < 4; ++c) {
    int id = (w * 4 + c) * 64 + lane;
    int kr = id >> 4, ck = id & 15;
    kp[c] = qk + (size_t)(b * SEQ + kr) * 4096 + 2048 + hh * DH + ((ck ^ (kr & 7)) * 8);
    int dr = id >> 3, cv = id & 7;
    vp[c] = vt + (size_t)(bh * DH + dr) * SEQ + ((cv ^ (dr & 7)) * 8);
    lofs[c] = (w * 4 + c) * 512;
  }

  auto STAGE = [&](int buf) {
    #pragma unroll
    for (int c = 0; c < 4; ++c) {
      gload16(kp[c], &sK[buf][0] + lofs[c]);
      gload16(vp[c], &sV[buf][0] + lofs[c]);
      kp[c] += 64 * 4096;
      vp[c] += 64;
    }
  };

  f32x16 accO[4];
  #pragma unroll
  for (int i = 0; i < 4; ++i)
    #pragma unroll
    for (int r = 0; r < 16; ++r) accO[i][r] = 0.f;
  float l_r = 0.f;

  auto COMPUTE = [&](int tt, int buf) {
    const int t0 = tt * 64;
    f32x16 accS[2];
    #pragma unroll
    for (int i = 0; i < 2; ++i)
      #pragma unroll
      for (int r = 0; r < 16; ++r) accS[i][r] = 0.f;
    #pragma unroll
    for (int kt = 0; kt < 2; ++kt) {
      const int row = kt * 32 + l31;
      #pragma unroll
      for (int kk = 0; kk < 8; ++kk) {
        const int cp = (kk * 2 + h2) ^ (lane & 7);
        bf16x8 kf = *(const bf16x8*)&sK[buf][row * 128 + cp * 8];
        accS[kt] = __builtin_amdgcn_mfma_f32_32x32x16_bf16(kf, qf[kk], accS[kt], 0, 0, 0);
      }
    }
    float rs = 0.f;
    if (t0 + 63 <= q0w) {
      #pragma unroll
      for (int kt = 0; kt < 2; ++kt)
        #pragma unroll
        for (int r = 0; r < 16; ++r) {
          float p = __builtin_amdgcn_exp2f(accS[kt][r]);
          rs += p;
          accS[kt][r] = p;
        }
    } else {
      const int qa = q0w + l31;
      #pragma unroll
      for (int kt = 0; kt < 2; ++kt)
        #pragma unroll
        for (int r = 0; r < 16; ++r) {
          int ka = t0 + kt * 32 + (r & 3) + 8 * (r >> 2) + 4 * h2;
          float p = (ka <= qa) ? __builtin_amdgcn_exp2f(accS[kt][r]) : 0.f;
          rs += p;
          accS[kt][r] = p;
        }
    }
    rs += __shfl_xor(rs, 32);
    l_r += rs;

    uint W[2][4][2];
    #pragma unroll
    for (int kt = 0; kt < 2; ++kt)
      #pragma unroll
      for (int bq = 0; bq < 4; ++bq)
        #pragma unroll
        for (int w2 = 0; w2 < 2; ++w2) {
          uint u0 = __float_as_uint(accS[kt][bq * 4 + w2 * 2]);
          uint u1 = __float_as_uint(accS[kt][bq * 4 + w2 * 2 + 1]);
          W[kt][bq][w2] = (u0 >> 16) | (u1 & 0xffff0000u);
        }
    #pragma unroll
    for (int kc = 0; kc < 4; ++kc) {
      const int kt = kc >> 1, pq = kc & 1;
      uint X0 = W[kt][2 * pq][0],     X1 = W[kt][2 * pq][1];
      uint Y0 = W[kt][2 * pq + 1][0], Y1 = W[kt][2 * pq + 1][1];
      uint sx0 = (uint)__shfl_xor((int)X0, 32);
      uint sx1 = (uint)__shfl_xor((int)X1, 32);
      uint sy0 = (uint)__shfl_xor((int)Y0, 32);
      uint sy1 = (uint)__shfl_xor((int)Y1, 32);
      union { uint u[4]; bf16x8 v; } pu;
      pu.u[0] = h2 ? sy0 : X0;
      pu.u[1] = h2 ? sy1 : X1;
      pu.u[2] = h2 ? Y0 : sx0;
      pu.u[3] = h2 ? Y1 : sx1;
      #pragma unroll
      for (int ds = 0; ds < 4; ++ds) {
        const int dr = ds * 32 + l31;
        const int cp = (kc * 2 + h2) ^ (lane & 7);
        bf16x8 vf = *(const bf16x8*)&sV[buf][dr * 64 + cp * 8];
        accO[ds] = __builtin_amdgcn_mfma_f32_32x32x16_bf16(pu.v, vf, accO[ds], 0, 0, 0);
      }
    }
  };

  const int ntile = 2 * qblk + 2;
  STAGE(0);
  #pragma unroll 1
  for (int tt = 0; tt < ntile - 1; ++tt) {
    STAGE((tt + 1) & 1);
    VMCNT(8);                 // tile tt's 8 loads done; tt+1's in flight
    ABAR();
    if (tt * 64 <= q0w + 31) COMPUTE(tt, tt & 1);
    ABAR();                   // seal buf before restage next iter
  }
  VMCNT(0);
  ABAR();
  if ((ntile - 1) * 64 <= q0w + 31) COMPUTE(ntile - 1, (ntile - 1) & 1);

  float linv = 1.f / l_r;
  #pragma unroll
  for (int r = 0; r < 16; ++r) {
    int qrel = (r & 3) + 8 * (r >> 2) + 4 * h2;
    float li = __shfl(linv, qrel);
    #pragma unroll
    for (int ds = 0; ds < 4; ++ds) {
      aout[(size_t)(b * SEQ + q0w + qrel) * HID + hh * DH + ds * 32 + l31] =
          f2bf(accO[ds][r] * li);
    }
  }
}

extern "C" void kernel_launch(void* const* d_in, const int* in_sizes, int n_in,
                              void* d_out, int out_size, void* d_ws, size_t ws_size,
                              hipStream_t stream) {
  const float* x     = (const float*)d_in[0];
  const float* rms_w = (const float*)d_in[1];
  const float* Wq    = (const float*)d_in[2];
  const float* Wk    = (const float*)d_in[3];
  const float* Wv    = (const float*)d_in[4];
  const float* Wo    = (const float*)d_in[5];
  float* out = (float*)d_out;

  char* ws = (char*)d_ws;
  ushort* WqkvT = (ushort*)ws; ws += (size_t)6144 * 2048 * 2;  // [6144][2048]
  ushort* WoT   = (ushort*)ws; ws += (size_t)2048 * 2048 * 2;  // [2048][2048]
  ushort* xn    = (ushort*)ws; ws += (size_t)4096 * 2048 * 2;  // [4096][2048]
  ushort* qkbuf = (ushort*)ws; ws += (size_t)4096 * 4096 * 2;  // [4096][4096]
  ushort* vt    = (ushort*)ws; ws += (size_t)4096 * 2048 * 2;  // [(b,h,d)][2048]
  ushort* aout  = (ushort*)ws; ws += (size_t)4096 * 2048 * 2;  // [4096][2048]

  // fused prep: 4 weight transposes + rmsnorm in one launch (co-scheduled)
  k_prep<<<dim3(64, 64, 5), dim3(32, 8), 0, stream>>>(Wq, Wk, Wv, Wo, WqkvT, WoT,
                                                      x, rms_w, xn);

  // QKV: M=4096, N=6144, K=2048.  256x256 tiles -> grid 24 x 16 (bn-fast).
  k_gemm10<<<dim3(24, 16), 512, 0, stream>>>(xn, WqkvT, qkbuf, vt);

  // attention: 512 blocks, balanced qblk pairing, 2-deep counted-vmcnt dbuf
  k_attn6<<<512, 256, 0, stream>>>(qkbuf, vt, aout);

  // out = attn @ Wo + x : M=4096, N=2048, K=2048
  k_gemm7o<<<dim3(16, 32), 256, 0, stream>>>(aout, WoT, out, x, 2048);
}

// Round 14
// 254.780 us; speedup vs baseline: 1.0276x; 1.0031x over previous
//
#include <hip/hip_runtime.h>
#include <math.h>

typedef __attribute__((ext_vector_type(8))) short bf16x8;
typedef __attribute__((ext_vector_type(4))) float f32x4;
typedef __attribute__((ext_vector_type(16))) float f32x16;

#define HID 2048
#define SEQ 2048
#define NH  16
#define DH  128
// QK_SCALE * log2(e), folded into Q at the QKV epilogue so softmax is exp2-direct
#define QS_LOG2E 0.0318793607f

__device__ __forceinline__ ushort f2bf(float f) {
  union { float f; unsigned u; } v; v.f = f;
  unsigned r = v.u + 0x7fffu + ((v.u >> 16) & 1u);
  return (ushort)(r >> 16);
}

// async global->LDS, 16B per lane. lds ptr must be wave-uniform; HW adds lane*16.
__device__ __forceinline__ void gload16(const ushort* g, ushort* l) {
  __builtin_amdgcn_global_load_lds((const __attribute__((address_space(1))) void*)g,
                                   (__attribute__((address_space(3))) void*)l,
                                   16, 0, 0);
}

#define VMCNT(n) asm volatile("s_waitcnt vmcnt(" #n ")" ::: "memory")
#define ABAR()   asm volatile("s_barrier" ::: "memory")

// ---------- fused prep: z<4 -> weight transpose fp32->bf16; z==4 -> RMSNorm ----------
__global__ __launch_bounds__(256) void k_prep(const float* __restrict__ W0,
                                              const float* __restrict__ W1,
                                              const float* __restrict__ W2,
                                              const float* __restrict__ W3,
                                              ushort* __restrict__ T0,
                                              ushort* __restrict__ T3,
                                              const float* __restrict__ x,
                                              const float* __restrict__ rw,
                                              ushort* __restrict__ xn) {
  const int z = blockIdx.z;
  if (z < 4) {
    __shared__ float t[32][33];
    const float* W = (z == 0) ? W0 : (z == 1) ? W1 : (z == 2) ? W2 : W3;
    ushort* Wt = (z == 3) ? T3 : (T0 + (size_t)z * 2048 * 2048);
    int n0 = blockIdx.x * 32, k0 = blockIdx.y * 32;
    int tx = threadIdx.x, ty = threadIdx.y;
    for (int i = ty; i < 32; i += 8)
      t[i][tx] = W[(size_t)(k0 + i) * HID + n0 + tx];
    __syncthreads();
    for (int i = ty; i < 32; i += 8)
      Wt[(size_t)(n0 + i) * HID + k0 + tx] = f2bf(t[tx][i]);
  } else {
    const int tid = threadIdx.y * 32 + threadIdx.x;
    const int row = blockIdx.y * 64 + blockIdx.x;
    const float* xr = x + (size_t)row * HID;
    int base = tid * 8;
    float4 a = *(const float4*)(xr + base);
    float4 c = *(const float4*)(xr + base + 4);
    float ss = a.x*a.x + a.y*a.y + a.z*a.z + a.w*a.w
             + c.x*c.x + c.y*c.y + c.z*c.z + c.w*c.w;
    #pragma unroll
    for (int off = 32; off > 0; off >>= 1) ss += __shfl_xor(ss, off);
    __shared__ float red[4];
    if ((tid & 63) == 0) red[tid >> 6] = ss;
    __syncthreads();
    float tot = red[0] + red[1] + red[2] + red[3];
    float sc = rsqrtf(tot * (1.0f / HID) + 1e-5f);
    float4 wa = *(const float4*)(rw + base);
    float4 wc = *(const float4*)(rw + base + 4);
    ushort h[8];
    h[0] = f2bf(a.x * sc * wa.x); h[1] = f2bf(a.y * sc * wa.y);
    h[2] = f2bf(a.z * sc * wa.z); h[3] = f2bf(a.w * sc * wa.w);
    h[4] = f2bf(c.x * sc * wc.x); h[5] = f2bf(c.y * sc * wc.y);
    h[6] = f2bf(c.z * sc * wc.z); h[7] = f2bf(c.w * sc * wc.w);
    int4 pk;
    pk.x = h[0] | ((int)h[1] << 16);
    pk.y = h[2] | ((int)h[3] << 16);
    pk.z = h[4] | ((int)h[5] << 16);
    pk.w = h[6] | ((int)h[7] << 16);
    *(int4*)&xn[(size_t)row * HID + base] = pk;
  }
}

// ---------- GEMM v12: R11's ring-4 counted cadence at 128x128 / 64KB / 2 blocks per CU ----------
// C = A[M][K] * Bt[N][K]^T, bf16.  BM=BN=128, 4 waves (2Mx2N), per-wave 64x64.
// Regions = k32 slices {A[128][32] 8KB | B[128][32] 8KB} = 16KB; ring-4 = 64KB
// -> 2 blocks/CU (vs R11's 1), grid 48x32 = 1536 blocks = EXACTLY 3 rounds at
// 2/CU (R11's 384@1/CU was 1.5 rounds, ~25% tail idle).  Cadence is R11's,
// verbatim: per region r: VMCNT(8) [retires r: 2 regions x 4 loads in flight]
// BAR; STAGE(r+3 -> slot (r-1)&3, WAR-sealed by this barrier); COMP(r)
// {8 ds_read_b128 + 16 MFMA, setprio-wrapped}.  Outstanding 12->8->12, never
// drained in-loop; tail drains 8/8/4/0.  Cooperative staging (every wave
// shares every region, same order) makes per-wave vmcnt + barrier a global
// completeness proof.  Swizzle: cp = ck^((row>>1)&3) on 64B rows (R11 math,
// measured 0 conflicts; 2 rows/bank = free).
// Epilogue: bn<16 -> Q*QS_LOG2E; bn<32 -> K; bn>=32 -> V transposed (8B packed).
__global__ __launch_bounds__(256, 2) void k_gemm12(const ushort* __restrict__ A,
                                                   const ushort* __restrict__ Bt,
                                                   ushort* __restrict__ obf,
                                                   ushort* __restrict__ vt) {
  constexpr int K = 2048, NR = 64;        // 64 k32-regions
  __shared__ ushort lds[4][8192];         // [slot][A 4096 | B 4096] ushorts
  const int tid = threadIdx.x;
  const int lane = tid & 63, w = tid >> 6;
  const int wr = w >> 1, wc = w & 1;      // 2M x 2N waves, 64x64 each
  const int g = lane >> 4, l15 = lane & 15;
  const int bm = blockIdx.y, bn = blockIdx.x;

  f32x4 acc[4][4];
  #pragma unroll
  for (int i = 0; i < 4; ++i)
    #pragma unroll
    for (int j = 0; j < 4; ++j) acc[i][j] = f32x4{0.f, 0.f, 0.f, 0.f};

  // staging sources: slot = L*256 + tid -> row = slot>>2, cp = slot&3,
  // src chunk ck = cp ^ ((row>>1)&3) (inverse of read swizzle); advance +=32/region
  const ushort* pA[2];
  const ushort* pB[2];
  #pragma unroll
  for (int L = 0; L < 2; ++L) {
    int row = L * 64 + (tid >> 2);
    int ck = (tid & 3) ^ ((row >> 1) & 3);
    pA[L] = &A[(size_t)(bm * 128 + row) * K + ck * 8];
    pB[L] = &Bt[(size_t)(bn * 128 + row) * K + ck * 8];
  }

  auto STAGE = [&](int slot) {
    ushort* base = lds[slot];
    #pragma unroll
    for (int L = 0; L < 2; ++L) {
      gload16(pA[L], base + L * 2048 + w * 512);
      pA[L] += 32;
    }
    #pragma unroll
    for (int L = 0; L < 2; ++L) {
      gload16(pB[L], base + 4096 + L * 2048 + w * 512);
      pB[L] += 32;
    }
  };

  auto COMP = [&](int slot) {
    const ushort* ra = lds[slot];
    const ushort* rb = ra + 4096;
    bf16x8 aF[4], bF[4];
    #pragma unroll
    for (int i = 0; i < 4; ++i) {
      int row = wr * 64 + i * 16 + l15;
      aF[i] = *(const bf16x8*)&ra[row * 32 + ((g ^ ((row >> 1) & 3)) * 8)];
    }
    #pragma unroll
    for (int j = 0; j < 4; ++j) {
      int row = wc * 64 + j * 16 + l15;
      bF[j] = *(const bf16x8*)&rb[row * 32 + ((g ^ ((row >> 1) & 3)) * 8)];
    }
    __builtin_amdgcn_s_setprio(1);
    #pragma unroll
    for (int i = 0; i < 4; ++i)
      #pragma unroll
      for (int j = 0; j < 4; ++j)
        acc[i][j] = __builtin_amdgcn_mfma_f32_16x16x32_bf16(aF[i], bF[j], acc[i][j], 0, 0, 0);
    __builtin_amdgcn_s_setprio(0);
  };

  STAGE(0); STAGE(1); STAGE(2);           // 12 loads outstanding

  #pragma unroll 1
  for (int r = 0; r <= NR - 4; ++r) {
    VMCNT(8); ABAR();                     // retires region r's 4 loads
    STAGE((r + 3) & 3);                   // into slot last read at r-1 (sealed)
    COMP(r & 3);
  }
  VMCNT(8); ABAR(); COMP((NR - 3) & 3);
  VMCNT(4); ABAR(); COMP((NR - 2) & 3);
  VMCNT(0); ABAR(); COMP((NR - 1) & 3);

  // C/D layout: col = lane&15, row = (lane>>4)*4 + r
  int rbase = bm * 128 + wr * 64 + g * 4;
  int cbase = bn * 128 + wc * 64 + l15;
  if (bn < 32) {
    const float sc = (bn < 16) ? QS_LOG2E : 1.0f;
    #pragma unroll
    for (int i = 0; i < 4; ++i) {
      #pragma unroll
      for (int j = 0; j < 4; ++j) {
        int col = cbase + j * 16;
        #pragma unroll
        for (int r = 0; r < 4; ++r) {
          int row = rbase + i * 16 + r;
          obf[(size_t)row * 4096 + col] = f2bf(acc[i][j][r] * sc);
        }
      }
    }
  } else {
    // V: transposed store vt[(b,h,d)][s]; r-direction = s contiguous -> 8B packed
    #pragma unroll
    for (int i = 0; i < 4; ++i) {
      int rowb = rbase + i * 16;          // multiple of 4
      int b = rowb >> 11, s = rowb & 2047;
      #pragma unroll
      for (int j = 0; j < 4; ++j) {
        int nv = cbase + j * 16 - 4096;
        int h = nv >> 7, d = nv & 127;
        uint lo = (uint)f2bf(acc[i][j][0]) | ((uint)f2bf(acc[i][j][1]) << 16);
        uint hi = (uint)f2bf(acc[i][j][2]) | ((uint)f2bf(acc[i][j][3]) << 16);
        uint2 pk = {lo, hi};
        *(uint2*)&vt[(size_t)((b * NH + h) * DH + d) * SEQ + s] = pk;
      }
    }
  }
}

// ---------- GEMM (R2-structure): out-proj ----------
__global__ __launch_bounds__(256) void k_gemm7o(const ushort* __restrict__ A,
                                                const ushort* __restrict__ Bt,
                                                float* __restrict__ ofl,
                                                const float* __restrict__ resid,
                                                int K) {
  __shared__ ushort sA[128 * 64];
  __shared__ ushort sB[128 * 64];
  const int tid = threadIdx.x;
  const int lane = tid & 63, w = tid >> 6;
  const int wr = w >> 1, wc = w & 1;
  const int bm = blockIdx.y, bn = blockIdx.x;
  const int g = lane >> 4, l15 = lane & 15;
  f32x4 acc[4][4];
  #pragma unroll
  for (int i = 0; i < 4; ++i)
    #pragma unroll
    for (int j = 0; j < 4; ++j) acc[i][j] = f32x4{0.f, 0.f, 0.f, 0.f};

  const ushort* ap[4];
  const ushort* bp[4];
  ushort* la[4];
  ushort* lb[4];
  #pragma unroll
  for (int c = 0; c < 4; ++c) {
    int id = (w * 4 + c) * 64 + lane;
    int r = id >> 3, ck = id & 7;
    int ke = (ck ^ (r & 7)) * 8;
    ap[c] = &A[(size_t)(bm * 128 + r) * K + ke];
    bp[c] = &Bt[(size_t)(bn * 128 + r) * K + ke];
    la[c] = ((ushort*)sA) + (w * 4 + c) * 512;
    lb[c] = ((ushort*)sB) + (w * 4 + c) * 512;
  }

  const int nt = K / 64;
  #pragma unroll 1
  for (int t = 0; t < nt; ++t) {
    #pragma unroll
    for (int c = 0; c < 4; ++c) {
      gload16(ap[c], la[c]);
      gload16(bp[c], lb[c]);
      ap[c] += 64;
      bp[c] += 64;
    }
    __syncthreads();
    #pragma unroll
    for (int kk = 0; kk < 2; ++kk) {
      bf16x8 aF[4], bF[4];
      #pragma unroll
      for (int i = 0; i < 4; ++i) {
        int row = wr * 64 + i * 16 + l15;
        int cp = (kk * 4 + g) ^ (lane & 7);
        aF[i] = *(const bf16x8*)&sA[row * 64 + cp * 8];
      }
      #pragma unroll
      for (int j = 0; j < 4; ++j) {
        int row = wc * 64 + j * 16 + l15;
        int cp = (kk * 4 + g) ^ (lane & 7);
        bF[j] = *(const bf16x8*)&sB[row * 64 + cp * 8];
      }
      #pragma unroll
      for (int i = 0; i < 4; ++i)
        #pragma unroll
        for (int j = 0; j < 4; ++j)
          acc[i][j] = __builtin_amdgcn_mfma_f32_16x16x32_bf16(aF[i], bF[j], acc[i][j], 0, 0, 0);
    }
    __syncthreads();
  }

  int rbase = bm * 128 + wr * 64 + g * 4;
  int cbase = bn * 128 + wc * 64 + l15;
  #pragma unroll
  for (int i = 0; i < 4; ++i) {
    #pragma unroll
    for (int j = 0; j < 4; ++j) {
      int col = cbase + j * 16;
      #pragma unroll
      for (int r = 0; r < 4; ++r) {
        int row = rbase + i * 16 + r;
        ofl[(size_t)row * HID + col] = acc[i][j][r] + resid[(size_t)row * HID + col];
      }
    }
  }
}

// ---------- flash attention v6 (R13): exp2 softmax + balanced map + counted dbuf ----------
__global__ __launch_bounds__(256, 2) void k_attn6(const ushort* __restrict__ qk,
                                                  const ushort* __restrict__ vt,
                                                  ushort* __restrict__ aout) {
  __shared__ ushort sK[2][64 * 128];
  __shared__ ushort sV[2][128 * 64];
  const int tid = threadIdx.x;
  const int lane = tid & 63, w = tid >> 6;
  const int h2 = lane >> 5;
  const int l31 = lane & 31;
  const int bid = blockIdx.x;
  const int t = bid >> 3;
  const int u = t & 31, v = t >> 5;
  const int bh = (bid & 7) + 8 * (u & 3);
  const int qblk = v ? 15 - (u >> 2) : (u >> 2);
  const int b = bh >> 4, hh = bh & 15;
  const int q0w = qblk * 128 + w * 32;

  bf16x8 qf[8];
  {
    const ushort* qbase = qk + (size_t)(b * SEQ + q0w + l31) * 4096 + hh * DH;
    #pragma unroll
    for (int kk = 0; kk < 8; ++kk) qf[kk] = *(const bf16x8*)&qbase[kk * 16 + h2 * 8];
  }

  const ushort* kp[4];
  const ushort* vp[4];
  int lofs[4];
  #pragma unroll
  for (int c = 0; c < 4; ++c) {
    int id = (w * 4 + c) * 64 + lane;
    int kr = id >> 4, ck = id & 15;
    kp[c] = qk + (size_t)(b * SEQ + kr) * 4096 + 2048 + hh * DH + ((ck ^ (kr & 7)) * 8);
    int dr = id >> 3, cv = id & 7;
    vp[c] = vt + (size_t)(bh * DH + dr) * SEQ + ((cv ^ (dr & 7)) * 8);
    lofs[c] = (w * 4 + c) * 512;
  }

  auto STAGE = [&](int buf) {
    #pragma unroll
    for (int c = 0; c < 4; ++c) {
      gload16(kp[c], &sK[buf][0] + lofs[c]);
      gload16(vp[c], &sV[buf][0] + lofs[c]);
      kp[c] += 64 * 4096;
      vp[c] += 64;
    }
  };

  f32x16 accO[4];
  #pragma unroll
  for (int i = 0; i < 4; ++i)
    #pragma unroll
    for (int r = 0; r < 16; ++r) accO[i][r] = 0.f;
  float l_r = 0.f;

  auto COMPUTE = [&](int tt, int buf) {
    const int t0 = tt * 64;
    f32x16 accS[2];
    #pragma unroll
    for (int i = 0; i < 2; ++i)
      #pragma unroll
      for (int r = 0; r < 16; ++r) accS[i][r] = 0.f;
    #pragma unroll
    for (int kt = 0; kt < 2; ++kt) {
      const int row = kt * 32 + l31;
      #pragma unroll
      for (int kk = 0; kk < 8; ++kk) {
        const int cp = (kk * 2 + h2) ^ (lane & 7);
        bf16x8 kf = *(const bf16x8*)&sK[buf][row * 128 + cp * 8];
        accS[kt] = __builtin_amdgcn_mfma_f32_32x32x16_bf16(kf, qf[kk], accS[kt], 0, 0, 0);
      }
    }
    float rs = 0.f;
    if (t0 + 63 <= q0w) {
      #pragma unroll
      for (int kt = 0; kt < 2; ++kt)
        #pragma unroll
        for (int r = 0; r < 16; ++r) {
          float p = __builtin_amdgcn_exp2f(accS[kt][r]);
          rs += p;
          accS[kt][r] = p;
        }
    } else {
      const int qa = q0w + l31;
      #pragma unroll
      for (int kt = 0; kt < 2; ++kt)
        #pragma unroll
        for (int r = 0; r < 16; ++r) {
          int ka = t0 + kt * 32 + (r & 3) + 8 * (r >> 2) + 4 * h2;
          float p = (ka <= qa) ? __builtin_amdgcn_exp2f(accS[kt][r]) : 0.f;
          rs += p;
          accS[kt][r] = p;
        }
    }
    rs += __shfl_xor(rs, 32);
    l_r += rs;

    uint W[2][4][2];
    #pragma unroll
    for (int kt = 0; kt < 2; ++kt)
      #pragma unroll
      for (int bq = 0; bq < 4; ++bq)
        #pragma unroll
        for (int w2 = 0; w2 < 2; ++w2) {
          uint u0 = __float_as_uint(accS[kt][bq * 4 + w2 * 2]);
          uint u1 = __float_as_uint(accS[kt][bq * 4 + w2 * 2 + 1]);
          W[kt][bq][w2] = (u0 >> 16) | (u1 & 0xffff0000u);
        }
    #pragma unroll
    for (int kc = 0; kc < 4; ++kc) {
      const int kt = kc >> 1, pq = kc & 1;
      uint X0 = W[kt][2 * pq][0],     X1 = W[kt][2 * pq][1];
      uint Y0 = W[kt][2 * pq + 1][0], Y1 = W[kt][2 * pq + 1][1];
      uint sx0 = (uint)__shfl_xor((int)X0, 32);
      uint sx1 = (uint)__shfl_xor((int)X1, 32);
      uint sy0 = (uint)__shfl_xor((int)Y0, 32);
      uint sy1 = (uint)__shfl_xor((int)Y1, 32);
      union { uint u[4]; bf16x8 v; } pu;
      pu.u[0] = h2 ? sy0 : X0;
      pu.u[1] = h2 ? sy1 : X1;
      pu.u[2] = h2 ? Y0 : sx0;
      pu.u[3] = h2 ? Y1 : sx1;
      #pragma unroll
      for (int ds = 0; ds < 4; ++ds) {
        const int dr = ds * 32 + l31;
        const int cp = (kc * 2 + h2) ^ (lane & 7);
        bf16x8 vf = *(const bf16x8*)&sV[buf][dr * 64 + cp * 8];
        accO[ds] = __builtin_amdgcn_mfma_f32_32x32x16_bf16(pu.v, vf, accO[ds], 0, 0, 0);
      }
    }
  };

  const int ntile = 2 * qblk + 2;
  STAGE(0);
  #pragma unroll 1
  for (int tt = 0; tt < ntile - 1; ++tt) {
    STAGE((tt + 1) & 1);
    VMCNT(8);
    ABAR();
    if (tt * 64 <= q0w + 31) COMPUTE(tt, tt & 1);
    ABAR();
  }
  VMCNT(0);
  ABAR();
  if ((ntile - 1) * 64 <= q0w + 31) COMPUTE(ntile - 1, (ntile - 1) & 1);

  float linv = 1.f / l_r;
  #pragma unroll
  for (int r = 0; r < 16; ++r) {
    int qrel = (r & 3) + 8 * (r >> 2) + 4 * h2;
    float li = __shfl(linv, qrel);
    #pragma unroll
    for (int ds = 0; ds < 4; ++ds) {
      aout[(size_t)(b * SEQ + q0w + qrel) * HID + hh * DH + ds * 32 + l31] =
          f2bf(accO[ds][r] * li);
    }
  }
}

extern "C" void kernel_launch(void* const* d_in, const int* in_sizes, int n_in,
                              void* d_out, int out_size, void* d_ws, size_t ws_size,
                              hipStream_t stream) {
  const float* x     = (const float*)d_in[0];
  const float* rms_w = (const float*)d_in[1];
  const float* Wq    = (const float*)d_in[2];
  const float* Wk    = (const float*)d_in[3];
  const float* Wv    = (const float*)d_in[4];
  const float* Wo    = (const float*)d_in[5];
  float* out = (float*)d_out;

  char* ws = (char*)d_ws;
  ushort* WqkvT = (ushort*)ws; ws += (size_t)6144 * 2048 * 2;  // [6144][2048]
  ushort* WoT   = (ushort*)ws; ws += (size_t)2048 * 2048 * 2;  // [2048][2048]
  ushort* xn    = (ushort*)ws; ws += (size_t)4096 * 2048 * 2;  // [4096][2048]
  ushort* qkbuf = (ushort*)ws; ws += (size_t)4096 * 4096 * 2;  // [4096][4096]
  ushort* vt    = (ushort*)ws; ws += (size_t)4096 * 2048 * 2;  // [(b,h,d)][2048]
  ushort* aout  = (ushort*)ws; ws += (size_t)4096 * 2048 * 2;  // [4096][2048]

  // fused prep: 4 weight transposes + rmsnorm in one launch (co-scheduled)
  k_prep<<<dim3(64, 64, 5), dim3(32, 8), 0, stream>>>(Wq, Wk, Wv, Wo, WqkvT, WoT,
                                                      x, rms_w, xn);

  // QKV: M=4096, N=6144, K=2048.  128x128 tiles -> grid 48 x 32 (bn-fast),
  // 1536 blocks = exactly 3 rounds at 2 blocks/CU.
  k_gemm12<<<dim3(48, 32), 256, 0, stream>>>(xn, WqkvT, qkbuf, vt);

  // attention: 512 blocks, balanced qblk pairing, 2-deep counted-vmcnt dbuf
  k_attn6<<<512, 256, 0, stream>>>(qkbuf, vt, aout);

  // out = attn @ Wo + x : M=4096, N=2048, K=2048
  k_gemm7o<<<dim3(16, 32), 256, 0, stream>>>(aout, WoT, out, x, 2048);
}